// Round 1
// baseline (440.250 us; speedup 1.0000x reference)
//
#include <hip/hip_runtime.h>
#include <hip/hip_bf16.h>
#include <math.h>

#define QLEN 512
#define MLENC 512
#define KLEN 1024   // QLEN + MLENC
#define BSZ 8
#define DMODEL 1024
#define NHEAD 16
#define DHEAD 64

typedef __hip_bfloat16 bf16;
typedef unsigned short u16;
typedef unsigned int u32;
typedef __attribute__((ext_vector_type(8))) short s16x8;
typedef __attribute__((ext_vector_type(4))) float f32x4;
typedef __attribute__((ext_vector_type(2))) unsigned int u32x2;

#define MFMA16(a, b, c) __builtin_amdgcn_mfma_f32_16x16x32_bf16(a, b, c, 0, 0, 0)

static __device__ __forceinline__ float b2f(bf16 x) { return __bfloat162float(x); }
static __device__ __forceinline__ bf16 f2b(float x) { return __float2bfloat16(x); }
static __device__ __forceinline__ u16 bbu(float x) {
    bf16 h = __float2bfloat16(x);
    return *reinterpret_cast<u16*>(&h);
}
static __device__ __forceinline__ float sh2f(u16 v) {
    return __uint_as_float(((u32)v) << 16);
}

static __device__ __forceinline__ void gl_lds16(const void* g, void* l) {
    __builtin_amdgcn_global_load_lds(
        (const __attribute__((address_space(1))) void*)g,
        (__attribute__((address_space(3))) void*)l, 16, 0, 0);
}

// ---------------------------------------------------------------------------
// One-time weight conversion f32 -> bf16 into ws.
// ---------------------------------------------------------------------------
__global__ __launch_bounds__(256) void wconv_kernel(const float* __restrict__ wq,
                                                    const float* __restrict__ wkv,
                                                    const float* __restrict__ wr,
                                                    const float* __restrict__ wo,
                                                    bf16* __restrict__ out) {
    int off = (blockIdx.x * 256 + threadIdx.x) * 8;
    const float* src;
    if (off < 1048576)       src = wq + off;
    else if (off < 3145728)  src = wkv + (off - 1048576);
    else if (off < 4194304)  src = wr + (off - 3145728);
    else                     src = wo + (off - 4194304);
    float4 f0 = *(const float4*)src;
    float4 f1 = *(const float4*)(src + 4);
    s16x8 v;
    v[0] = (short)bbu(f0.x); v[1] = (short)bbu(f0.y);
    v[2] = (short)bbu(f0.z); v[3] = (short)bbu(f0.w);
    v[4] = (short)bbu(f1.x); v[5] = (short)bbu(f1.y);
    v[6] = (short)bbu(f1.z); v[7] = (short)bbu(f1.w);
    *(s16x8*)((short*)out + off) = v;
}

// ---------------------------------------------------------------------------
// LayerNorm of content+mems into cat[KLEN*BSZ, DMODEL] (bf16).
// ---------------------------------------------------------------------------
__global__ __launch_bounds__(256) void ln_kernel(const float* __restrict__ content,
                                                 const float* __restrict__ mems,
                                                 const float* __restrict__ g,
                                                 const float* __restrict__ bet,
                                                 bf16* __restrict__ cat) {
    int row = blockIdx.x;
    int tid = threadIdx.x;
    const float* src = (row < MLENC * BSZ)
        ? mems + (size_t)row * DMODEL
        : content + (size_t)(row - MLENC * BSZ) * DMODEL;

    float x[4];
    float s = 0.f, ss = 0.f;
#pragma unroll
    for (int l = 0; l < 4; ++l) {
        int d = l * 256 + tid;
        x[l] = src[d];
        s += x[l];
        ss += x[l] * x[l];
    }
#pragma unroll
    for (int off = 32; off > 0; off >>= 1) {
        s  += __shfl_xor(s, off);
        ss += __shfl_xor(ss, off);
    }
    __shared__ float red[8];
    int wid = tid >> 6;
    if ((tid & 63) == 0) { red[wid * 2] = s; red[wid * 2 + 1] = ss; }
    __syncthreads();
    s  = red[0] + red[2] + red[4] + red[6];
    ss = red[1] + red[3] + red[5] + red[7];
    float mu  = s * (1.f / DMODEL);
    float var = ss * (1.f / DMODEL) - mu * mu;
    float rs  = rsqrtf(var + 1e-5f);
    bf16* dst = cat + (size_t)row * DMODEL;
#pragma unroll
    for (int l = 0; l < 4; ++l) {
        int d = l * 256 + tid;
        dst[d] = f2b((x[l] - mu) * rs * g[d] + bet[d]);
    }
}

// ---------------------------------------------------------------------------
// MFMA GEMM 128x128 tile, BK=32 (for the big kv GEMM).
// ---------------------------------------------------------------------------
template <int MODE, bool AF32, bool BF32>
__global__ __launch_bounds__(256) void gemm_mfma(const void* __restrict__ Av,
                                                 const void* __restrict__ Bv,
                                                 const float* __restrict__ bias,
                                                 const bf16* __restrict__ resid,
                                                 bf16* __restrict__ Cb,
                                                 float* __restrict__ Cf,
                                                 int Mr, int N) {
    __shared__ short As[128 * 32];
    __shared__ short Bs[128 * 32];

    int m0 = blockIdx.y * 128, n0 = blockIdx.x * 128;
    int tid = threadIdx.x;
    int w = tid >> 6, lane = tid & 63, l15 = lane & 15, quad = lane >> 4;
    int wm = w & 1, wn = w >> 1;

    const short* Ab = (const short*)Av;
    const float* Af = (const float*)Av;
    const short* Bb = (const short*)Bv;
    const float* Bf = (const float*)Bv;

    f32x4 acc[4][4];
#pragma unroll
    for (int i = 0; i < 4; ++i)
#pragma unroll
        for (int j = 0; j < 4; ++j) acc[i][j] = (f32x4){0.f, 0.f, 0.f, 0.f};

    for (int kt = 0; kt < 1024; kt += 32) {
        __syncthreads();
        if (!AF32) {
#pragma unroll
            for (int li = 0; li < 2; ++li) {
                int id = (li * 4 + w) * 64 + lane;
                int row = id >> 2, kc = (id & 3) * 8;
                gl_lds16(Ab + ((size_t)(m0 + row) * 1024 + kt + kc),
                         &As[(li * 4 + w) * 512]);
            }
        } else {
            int m = tid >> 1, kc = (tid & 1) * 16;
            const float* src = Af + (size_t)(m0 + m) * 1024 + kt + kc;
            u32* dst = (u32*)&As[m * 32 + kc];
#pragma unroll
            for (int q2 = 0; q2 < 4; ++q2) {
                float4 f = *(const float4*)(src + q2 * 4);
                dst[q2 * 2]     = ((u32)bbu(f.y) << 16) | bbu(f.x);
                dst[q2 * 2 + 1] = ((u32)bbu(f.w) << 16) | bbu(f.z);
            }
        }
        if (!BF32) {
#pragma unroll
            for (int li = 0; li < 2; ++li) {
                int id = (li * 4 + w) * 64 + lane;
                int row = id >> 2, kc = (id & 3) * 8;
                gl_lds16(Bb + ((size_t)(n0 + row) * 1024 + kt + kc),
                         &Bs[(li * 4 + w) * 512]);
            }
        } else {
            int nn = tid >> 1, kc = (tid & 1) * 16;
            const float* src = Bf + (size_t)(n0 + nn) * 1024 + kt + kc;
            u32* dst = (u32*)&Bs[nn * 32 + kc];
#pragma unroll
            for (int q2 = 0; q2 < 4; ++q2) {
                float4 f = *(const float4*)(src + q2 * 4);
                dst[q2 * 2]     = ((u32)bbu(f.y) << 16) | bbu(f.x);
                dst[q2 * 2 + 1] = ((u32)bbu(f.w) << 16) | bbu(f.z);
            }
        }
        __syncthreads();

        s16x8 af[4], bfr[4];
#pragma unroll
        for (int mb = 0; mb < 4; ++mb)
            af[mb] = *(const s16x8*)&As[(wm * 64 + mb * 16 + l15) * 32 + quad * 8];
#pragma unroll
        for (int nb = 0; nb < 4; ++nb)
            bfr[nb] = *(const s16x8*)&Bs[(wn * 64 + nb * 16 + l15) * 32 + quad * 8];
#pragma unroll
        for (int mb = 0; mb < 4; ++mb)
#pragma unroll
            for (int nb = 0; nb < 4; ++nb)
                acc[mb][nb] = MFMA16(af[mb], bfr[nb], acc[mb][nb]);
    }

#pragma unroll
    for (int mb = 0; mb < 4; ++mb) {
#pragma unroll
        for (int nb = 0; nb < 4; ++nb) {
#pragma unroll
            for (int r = 0; r < 4; ++r) {
                int m = m0 + wm * 64 + mb * 16 + quad * 4 + r;
                int col = n0 + wn * 64 + nb * 16 + l15;
                float v = acc[mb][nb][r];
                if (MODE >= 1) v += bias[col];
                if (MODE == 2) {
                    float rv = b2f(resid[(size_t)m * N + col]);
                    Cf[(size_t)m * N + col] = rv + fmaxf(v, 0.f);
                } else {
                    Cb[(size_t)m * N + col] = f2b(v);
                }
            }
        }
    }
}

// ---------------------------------------------------------------------------
// MFMA GEMM 64x128 tile (doubles grid for the small M GEMMs q/r/o).
// ---------------------------------------------------------------------------
template <int MODE, bool AF32, bool BF32>
__global__ __launch_bounds__(256) void gemm64(const void* __restrict__ Av,
                                              const void* __restrict__ Bv,
                                              const float* __restrict__ bias,
                                              const bf16* __restrict__ resid,
                                              bf16* __restrict__ Cb,
                                              float* __restrict__ Cf,
                                              int Mr, int N) {
    __shared__ short As[64 * 32];
    __shared__ short Bs[128 * 32];

    int m0 = blockIdx.y * 64, n0 = blockIdx.x * 128;
    int tid = threadIdx.x;
    int w = tid >> 6, lane = tid & 63, l15 = lane & 15, quad = lane >> 4;

    const short* Ab = (const short*)Av;
    const float* Af = (const float*)Av;
    const short* Bb = (const short*)Bv;
    const float* Bf = (const float*)Bv;

    f32x4 acc[4][2];
#pragma unroll
    for (int i = 0; i < 4; ++i)
#pragma unroll
        for (int j = 0; j < 2; ++j) acc[i][j] = (f32x4){0.f, 0.f, 0.f, 0.f};

    for (int kt = 0; kt < 1024; kt += 32) {
        __syncthreads();
        if (!AF32) {
            int id = w * 64 + lane;
            int row = id >> 2, kc = (id & 3) * 8;
            gl_lds16(Ab + ((size_t)(m0 + row) * 1024 + kt + kc), &As[w * 512]);
        } else {
            int m = tid >> 2, kc = (tid & 3) * 8;
            const float* src = Af + (size_t)(m0 + m) * 1024 + kt + kc;
            u32* dst = (u32*)&As[m * 32 + kc];
#pragma unroll
            for (int q2 = 0; q2 < 2; ++q2) {
                float4 f = *(const float4*)(src + q2 * 4);
                dst[q2 * 2]     = ((u32)bbu(f.y) << 16) | bbu(f.x);
                dst[q2 * 2 + 1] = ((u32)bbu(f.w) << 16) | bbu(f.z);
            }
        }
        if (!BF32) {
#pragma unroll
            for (int li = 0; li < 2; ++li) {
                int id = (li * 4 + w) * 64 + lane;
                int row = id >> 2, kc = (id & 3) * 8;
                gl_lds16(Bb + ((size_t)(n0 + row) * 1024 + kt + kc),
                         &Bs[(li * 4 + w) * 512]);
            }
        } else {
            int nn = tid >> 1, kc = (tid & 1) * 16;
            const float* src = Bf + (size_t)(n0 + nn) * 1024 + kt + kc;
            u32* dst = (u32*)&Bs[nn * 32 + kc];
#pragma unroll
            for (int q2 = 0; q2 < 4; ++q2) {
                float4 f = *(const float4*)(src + q2 * 4);
                dst[q2 * 2]     = ((u32)bbu(f.y) << 16) | bbu(f.x);
                dst[q2 * 2 + 1] = ((u32)bbu(f.w) << 16) | bbu(f.z);
            }
        }
        __syncthreads();

        s16x8 af[4], bfr[2];
#pragma unroll
        for (int mb = 0; mb < 4; ++mb)
            af[mb] = *(const s16x8*)&As[(mb * 16 + l15) * 32 + quad * 8];
#pragma unroll
        for (int nb = 0; nb < 2; ++nb)
            bfr[nb] = *(const s16x8*)&Bs[(w * 32 + nb * 16 + l15) * 32 + quad * 8];
#pragma unroll
        for (int mb = 0; mb < 4; ++mb)
#pragma unroll
            for (int nb = 0; nb < 2; ++nb)
                acc[mb][nb] = MFMA16(af[mb], bfr[nb], acc[mb][nb]);
    }

#pragma unroll
    for (int mb = 0; mb < 4; ++mb) {
#pragma unroll
        for (int nb = 0; nb < 2; ++nb) {
#pragma unroll
            for (int r = 0; r < 4; ++r) {
                int m = m0 + mb * 16 + quad * 4 + r;
                int col = n0 + w * 32 + nb * 16 + l15;
                float v = acc[mb][nb][r];
                if (MODE >= 1) v += bias[col];
                if (MODE == 2) {
                    float rv = b2f(resid[(size_t)m * N + col]);
                    Cf[(size_t)m * N + col] = rv + fmaxf(v, 0.f);
                } else {
                    Cb[(size_t)m * N + col] = f2b(v);
                }
            }
        }
    }
}

// ---------------------------------------------------------------------------
// Fused MFMA flash attention with on-the-fly rel-shift (no Sr tensor).
// SPLIT=true: flash-decode style split-K over KLEN (2 splits of 512).
// Each split block walks 16 K-steps and emits unnormalized O (f32) plus
// running (m, l) per row; combine_kernel merges. The rel-shift wrap branch
// (need2: j0 >= i0+483) lives entirely inside split 1, and need1 covers all
// of split 0, so the existing flag formulas generalize to j0base != 0.
// ---------------------------------------------------------------------------
template <bool SPLIT>
__global__ __launch_bounds__(256) void attn_mfma(const bf16* __restrict__ qb,
                                                 const bf16* __restrict__ kv,
                                                 const bf16* __restrict__ rp,
                                                 bf16* __restrict__ vec,
                                                 float* __restrict__ Op,
                                                 float* __restrict__ mlbuf) {
    __shared__ u16 Ks[32][72];     // K tile [j][d]
    __shared__ u16 Vr[2][2048];    // V tile raw, ping-pong glds dest
    __shared__ u16 Vt[64][40];     // V transposed [d][j]
    __shared__ u16 Ps[4][16][40];  // per-wave P
    __shared__ u16 Ms[4][16][56];  // per-wave banded-matmul strip (48 used)

    int bid = blockIdx.x;
    int sp = SPLIT ? (bid >> 10) : 0;
    int b2 = bid & 1023;
    int it = b2 & 7, n = (b2 >> 3) & 15, b = b2 >> 7;
    int i0 = it * 64;
    int j0base = sp * 512;
    int NST = SPLIT ? 16 : 32;
    int tid = threadIdx.x;
    int w = tid >> 6, lane = tid & 63, l15 = lane & 15, quad = lane >> 4;

    const short* qs = (const short*)qb;
    const short* kvs = (const short*)kv;
    const short* rs = (const short*)rp;

    // Q fragments: rows +0 (aq) and +1 (as, for wrap branch)
    size_t qoff = (((size_t)(i0 + w * 16 + l15) * 8) + b) * 1024 + n * 64 + quad * 8;
    s16x8 aq0 = *(const s16x8*)(qs + qoff);
    s16x8 aq1 = *(const s16x8*)(qs + qoff + 32);
    int qrow1 = i0 + w * 16 + l15 + 1; if (qrow1 > 511) qrow1 = 511;  // unused when clamped
    size_t qoffs = (((size_t)qrow1 * 8) + b) * 1024 + n * 64 + quad * 8;
    s16x8 as0 = *(const s16x8*)(qs + qoffs);
    s16x8 as1 = *(const s16x8*)(qs + qoffs + 32);

    f32x4 O0 = {0.f,0.f,0.f,0.f}, O1 = O0, O2 = O0, O3 = O0;
    float mrun[4], lrun[4];
#pragma unroll
    for (int r = 0; r < 4; ++r) { mrun[r] = -INFINITY; lrun[r] = 0.f; }

    f32x4 z = (f32x4){0.f, 0.f, 0.f, 0.f};
    int ibase = i0 + w * 16 + quad * 4;

    int jlK = tid >> 3, dcK = (tid & 7) * 8;   // K/V stage mapping
    int dV = lane, jV = w * 8;                 // V transpose mapping
    int wrow = (3 - w) * 16 + l15;             // W-window row offset for this wave

    // load 6 W-fragments (3 tiles x 2 k-halves) for window base `ubase`
    auto loadW = [&](int ubase, s16x8* dst) {
#pragma unroll
        for (int ntl = 0; ntl < 3; ++ntl) {
            int u = ubase + wrow + ntl * 16;
            u = u < 0 ? 0 : (u > 1023 ? 1023 : u);
            const short* p = rs + (size_t)u * 1024 + n * 64 + quad * 8;
            dst[ntl * 2]     = *(const s16x8*)p;
            dst[ntl * 2 + 1] = *(const s16x8*)(p + 32);
        }
    };
    // banded matmul + anti-diagonal gather (per-wave, same-wave DS ordering)
    auto bandM = [&](const s16x8* wf, s16x8 a0, s16x8 a1, float* ta, float* tb) {
        f32x4 m[3];
#pragma unroll
        for (int ntl = 0; ntl < 3; ++ntl) {
            m[ntl] = MFMA16(a0, wf[ntl * 2], z);
            m[ntl] = MFMA16(a1, wf[ntl * 2 + 1], m[ntl]);
        }
#pragma unroll
        for (int ntl = 0; ntl < 3; ++ntl)
#pragma unroll
            for (int r = 0; r < 4; ++r)
                Ms[w][quad * 4 + r][ntl * 16 + l15] = bbu(m[ntl][r]);
        __asm__ __volatile__("s_waitcnt lgkmcnt(0)" ::: "memory");
#pragma unroll
        for (int r = 0; r < 4; ++r) {
            int lr = quad * 4 + r;
            ta[r] = sh2f(Ms[w][lr][l15 - lr + 15]);
            tb[r] = sh2f(Ms[w][lr][l15 + 31 - lr]);
        }
        __asm__ __volatile__("s_waitcnt lgkmcnt(0)" ::: "memory");
    };

    s16x8 wcur[6], wnxt[6], w2t[6];
    bool need1c = (j0base <= i0 + 576);        // all of split 0; true at entry of split 1 too
    bool need2c = (j0base >= i0 + 483);        // only split 1 with i0 == 0

    // prologue: stage K tile, V tile, W window for first step of this split
    {
        size_t base = ((size_t)((j0base + jlK) * 8 + b)) * 2048 + n * 64 + dcK;
        s16x8 k0 = *(const s16x8*)(kvs + base);
        gl_lds16(kvs + base + 1024, &Vr[0][w * 512]);
        *(s16x8*)&Ks[jlK][dcK] = k0;
        loadW(448 + j0base - i0, wcur);
    }

    for (int st = 0; st < NST; ++st) {
        int p = st & 1;
        int j0 = j0base + st * 32;
        int j0n = (j0 + 32) & 1023;        // wrapped for addressing safety

        __syncthreads();   // barrier A: prev PV done; Ks/Vr[p] visible

        // ---- prefetch next step ----
        size_t basen = ((size_t)((j0n + jlK) * 8 + b)) * 2048 + n * 64 + dcK;
        s16x8 kreg = *(const s16x8*)(kvs + basen);
        gl_lds16(kvs + basen + 1024, &Vr[1 - p][w * 512]);
        int j0p = j0 + 32;
        bool need1n = (j0p <= i0 + 576);
        bool need2n = (j0p >= i0 + 483);
        loadW(need1n ? (448 + j0p - i0) : (j0p - i0 - 577), wnxt);
        if (need1c && need2c) loadW(j0 - i0 - 577, w2t);   // mixed step: W2 inline

        // ---- transpose Vr[p] -> Vt ----
        {
            s16x8 vv;
#pragma unroll
            for (int q2 = 0; q2 < 8; ++q2) vv[q2] = (short)Vr[p][(jV + q2) * 64 + dV];
            *(s16x8*)&Vt[dV][jV] = vv;
        }

        // ---- AC = Q K^T ----
        s16x8 bk00 = *(const s16x8*)&Ks[l15][quad * 8];
        s16x8 bk01 = *(const s16x8*)&Ks[l15][32 + quad * 8];
        s16x8 bk10 = *(const s16x8*)&Ks[16 + l15][quad * 8];
        s16x8 bk11 = *(const s16x8*)&Ks[16 + l15][32 + quad * 8];
        f32x4 s0 = MFMA16(aq0, bk00, z); s0 = MFMA16(aq1, bk01, s0);
        f32x4 s1 = MFMA16(aq0, bk10, z); s1 = MFMA16(aq1, bk11, s1);

        // ---- BD bands ----
        float t1a[4] = {0.f,0.f,0.f,0.f}, t1b[4] = {0.f,0.f,0.f,0.f};
        float t2a[4] = {0.f,0.f,0.f,0.f}, t2b[4] = {0.f,0.f,0.f,0.f};
        if (need1c) bandM(wcur, aq0, aq1, t1a, t1b);
        if (need2c) bandM(need1c ? w2t : wcur, as0, as1, t2a, t2b);

        // ---- select + scale ----
#pragma unroll
        for (int r = 0; r < 4; ++r) {
            int rr = w * 16 + quad * 4 + r;
            int dj0 = j0 + l15 - i0 - rr;
            int dj1 = dj0 + 16;
            float bd0 = (dj0 <= 512) ? t1a[r] : ((dj0 == 513) ? 0.f : t2a[r]);
            float bd1 = (dj1 <= 512) ? t1b[r] : ((dj1 == 513) ? 0.f : t2b[r]);
            s0[r] = (s0[r] + bd0) * 0.125f;
            s1[r] = (s1[r] + bd1) * 0.125f;
        }

        // ---- online softmax + P to LDS ----
#pragma unroll
        for (int r = 0; r < 4; ++r) {
            float ml = fmaxf(s0[r], s1[r]);
            ml = fmaxf(ml, __shfl_xor(ml, 1));
            ml = fmaxf(ml, __shfl_xor(ml, 2));
            ml = fmaxf(ml, __shfl_xor(ml, 4));
            ml = fmaxf(ml, __shfl_xor(ml, 8));
            float mn = fmaxf(mrun[r], ml);
            float p0 = __expf(s0[r] - mn);
            float p1 = __expf(s1[r] - mn);
            float ps = p0 + p1;
            ps += __shfl_xor(ps, 1);
            ps += __shfl_xor(ps, 2);
            ps += __shfl_xor(ps, 4);
            ps += __shfl_xor(ps, 8);
            float al = __expf(mrun[r] - mn);
            lrun[r] = lrun[r] * al + ps;
            mrun[r] = mn;
            O0[r] *= al; O1[r] *= al; O2[r] *= al; O3[r] *= al;
            Ps[w][quad * 4 + r][l15]      = bbu(p0);
            Ps[w][quad * 4 + r][16 + l15] = bbu(p1);
        }

        __syncthreads();   // barrier B: Vt+Ps visible; drains V glds

        // ---- PV ----
        s16x8 ap = *(const s16x8*)&Ps[w][l15][quad * 8];
        s16x8 bv0 = *(const s16x8*)&Vt[l15][quad * 8];
        s16x8 bv1 = *(const s16x8*)&Vt[16 + l15][quad * 8];
        s16x8 bv2 = *(const s16x8*)&Vt[32 + l15][quad * 8];
        s16x8 bv3 = *(const s16x8*)&Vt[48 + l15][quad * 8];
        O0 = MFMA16(ap, bv0, O0);
        O1 = MFMA16(ap, bv1, O1);
        O2 = MFMA16(ap, bv2, O2);
        O3 = MFMA16(ap, bv3, O3);

        // ---- stage next K tile; roll W regs/flags ----
        *(s16x8*)&Ks[jlK][dcK] = kreg;
#pragma unroll
        for (int i = 0; i < 6; ++i) wcur[i] = wnxt[i];
        need1c = need1n;
        need2c = need2n;
    }

    if (!SPLIT) {
#pragma unroll
        for (int r = 0; r < 4; ++r) {
            float inv = 1.f / lrun[r];
            int ig = ibase + r;
            size_t o = ((size_t)ig * 8 + b) * 1024 + n * 64;
            vec[o + l15]      = f2b(O0[r] * inv);
            vec[o + 16 + l15] = f2b(O1[r] * inv);
            vec[o + 32 + l15] = f2b(O2[r] * inv);
            vec[o + 48 + l15] = f2b(O3[r] * inv);
        }
    } else {
        // unnormalized O (f32) + running (m, l) per (row, head)
#pragma unroll
        for (int r = 0; r < 4; ++r) {
            int ig = ibase + r;
            size_t row = (size_t)ig * 8 + b;
            float* od = Op + (size_t)sp * 4194304 + row * 1024 + n * 64;
            od[l15]      = O0[r];
            od[16 + l15] = O1[r];
            od[32 + l15] = O2[r];
            od[48 + l15] = O3[r];
            if (l15 == 0) {
                float* mlp = mlbuf + (size_t)sp * 131072 + row * 32 + n * 2;
                mlp[0] = mrun[r];
                mlp[1] = lrun[r];
            }
        }
    }
}

// ---------------------------------------------------------------------------
// Merge the 2 split-K partials: O = (O0*w0 + O1*w1) / (l0*w0 + l1*w1),
// wi = exp(mi - max(m0, m1)). One block per output row (4096), 256 thr x 4 f32.
// ---------------------------------------------------------------------------
__global__ __launch_bounds__(256) void combine_kernel(const float* __restrict__ Op,
                                                      const float* __restrict__ mlbuf,
                                                      bf16* __restrict__ vec) {
    int row = blockIdx.x;          // (i*8 + b), 0..4095
    int col = threadIdx.x * 4;     // 0..1023, stays within one 64-wide head
    int n = col >> 6;

    const float* mlp0 = mlbuf + (size_t)row * 32 + n * 2;
    const float* mlp1 = mlp0 + 131072;
    float m0 = mlp0[0], l0 = mlp0[1];
    float m1 = mlp1[0], l1 = mlp1[1];
    float m = fmaxf(m0, m1);
    float w0 = __expf(m0 - m), w1 = __expf(m1 - m);
    float inv = 1.f / (l0 * w0 + l1 * w1);

    const float* o0 = Op + (size_t)row * 1024 + col;
    const float* o1 = o0 + 4194304;
    float4 a = *(const float4*)o0;
    float4 c = *(const float4*)o1;
    float r0 = (a.x * w0 + c.x * w1) * inv;
    float r1 = (a.y * w0 + c.y * w1) * inv;
    float r2 = (a.z * w0 + c.z * w1) * inv;
    float r3 = (a.w * w0 + c.w * w1) * inv;
    u32x2 pk;
    pk[0] = ((u32)bbu(r1) << 16) | bbu(r0);
    pk[1] = ((u32)bbu(r3) << 16) | bbu(r2);
    *(u32x2*)((short*)vec + (size_t)row * 1024 + col) = pk;
}

// ---------------------------------------------------------------------------
extern "C" void kernel_launch(void* const* d_in, const int* in_sizes, int n_in,
                              void* d_out, int out_size, void* d_ws, size_t ws_size,
                              hipStream_t stream) {
    const float* content = (const float*)d_in[0];
    const float* mems    = (const float*)d_in[1];
    const float* r       = (const float*)d_in[2];
    const float* q_bias  = (const float*)d_in[3];
    // d_in[4] = mask (all false) -> ignored
    const float* W_q     = (const float*)d_in[5];
    const float* W_kv    = (const float*)d_in[6];
    const float* W_r     = (const float*)d_in[7];
    const float* b_r     = (const float*)d_in[8];
    const float* W_o     = (const float*)d_in[9];
    const float* b_o     = (const float*)d_in[10];
    const float* ln_g    = (const float*)d_in[11];
    const float* ln_b    = (const float*)d_in[12];

    bf16* ws   = (bf16*)d_ws;
    bf16* cat  = ws;                       // [8192,1024]
    bf16* kv   = cat + 8388608;            // [8192,2048]
    bf16* qb   = kv + 16777216;            // [4096,1024]
    bf16* rp   = qb + 4194304;             // [1024,1024]
    bf16* vecb = rp + 1048576;             // [4096,1024]
    bf16* Wb   = vecb + 4194304;           // 5,242,880 bf16 weights
    bf16* catc = cat + (size_t)MLENC * BSZ * DMODEL;

    bf16* Wqb  = Wb;
    bf16* Wkvb = Wb + 1048576;
    bf16* Wrb  = Wb + 3145728;
    bf16* Wob  = Wb + 4194304;

    const size_t FULLW_BYTES = (size_t)(34603008 + 5242880) * 2;  // 79,691,776
    // split-K partials: O f32 [2][4096][1024] (33.5 MB) + ml f32 [2][4096][16][2] (1 MB)
    float* Opart = (float*)(Wb + 5242880);
    float* mlbuf = Opart + 8388608;
    const size_t SPLIT_BYTES = FULLW_BYTES + (size_t)(8388608 + 262144) * 4;  // 114,294,784
    bool fullw = ws_size >= FULLW_BYTES;
    bool dosplit = ws_size >= SPLIT_BYTES;

    ln_kernel<<<KLEN * BSZ, 256, 0, stream>>>(content, mems, ln_g, ln_b, cat);

    if (fullw) {
        wconv_kernel<<<2560, 256, 0, stream>>>(W_q, W_kv, W_r, W_o, Wb);

        gemm_mfma<0, false, false><<<dim3(16, 64), 256, 0, stream>>>(
            cat, Wkvb, nullptr, nullptr, kv, nullptr, 8192, 2048);
        gemm64<1, false, false><<<dim3(8, 64), 256, 0, stream>>>(
            catc, Wqb, q_bias, nullptr, qb, nullptr, 4096, 1024);
        gemm64<1, true, false><<<dim3(8, 16), 256, 0, stream>>>(
            r, Wrb, b_r, nullptr, rp, nullptr, 1024, 1024);
    } else {
        gemm_mfma<0, false, true><<<dim3(16, 64), 256, 0, stream>>>(
            cat, W_kv, nullptr, nullptr, kv, nullptr, 8192, 2048);
        gemm64<1, false, true><<<dim3(8, 64), 256, 0, stream>>>(
            catc, W_q, q_bias, nullptr, qb, nullptr, 4096, 1024);
        gemm64<1, true, true><<<dim3(8, 16), 256, 0, stream>>>(
            r, W_r, b_r, nullptr, rp, nullptr, 1024, 1024);
    }

    if (dosplit) {
        attn_mfma<true><<<2048, 256, 0, stream>>>(qb, kv, rp, nullptr, Opart, mlbuf);
        combine_kernel<<<4096, 256, 0, stream>>>(Opart, mlbuf, vecb);
    } else {
        attn_mfma<false><<<1024, 256, 0, stream>>>(qb, kv, rp, vecb, nullptr, nullptr);
    }

    if (fullw) {
        gemm64<2, false, false><<<dim3(8, 64), 256, 0, stream>>>(
            vecb, Wob, b_o, catc, nullptr, (float*)d_out, 4096, 1024);
    } else {
        gemm64<2, false, true><<<dim3(8, 64), 256, 0, stream>>>(
            vecb, W_o, b_o, catc, nullptr, (float*)d_out, 4096, 1024);
    }
}

// Round 2
// 378.147 us; speedup vs baseline: 1.1642x; 1.1642x over previous
//
#include <hip/hip_runtime.h>
#include <hip/hip_bf16.h>
#include <math.h>

#define QLEN 512
#define MLENC 512
#define KLEN 1024   // QLEN + MLENC
#define BSZ 8
#define DMODEL 1024
#define NHEAD 16
#define DHEAD 64

typedef __hip_bfloat16 bf16;
typedef unsigned short u16;
typedef unsigned int u32;
typedef __attribute__((ext_vector_type(8))) short s16x8;
typedef __attribute__((ext_vector_type(4))) float f32x4;

#define MFMA16(a, b, c) __builtin_amdgcn_mfma_f32_16x16x32_bf16(a, b, c, 0, 0, 0)

static __device__ __forceinline__ float b2f(bf16 x) { return __bfloat162float(x); }
static __device__ __forceinline__ bf16 f2b(float x) { return __float2bfloat16(x); }
static __device__ __forceinline__ u16 bbu(float x) {
    bf16 h = __float2bfloat16(x);
    return *reinterpret_cast<u16*>(&h);
}
static __device__ __forceinline__ float sh2f(u16 v) {
    return __uint_as_float(((u32)v) << 16);
}

static __device__ __forceinline__ void gl_lds16(const void* g, void* l) {
    __builtin_amdgcn_global_load_lds(
        (const __attribute__((address_space(1))) void*)g,
        (__attribute__((address_space(3))) void*)l, 16, 0, 0);
}

// ---------------------------------------------------------------------------
// One-time weight conversion f32 -> bf16 into ws.
// ---------------------------------------------------------------------------
__global__ __launch_bounds__(256) void wconv_kernel(const float* __restrict__ wq,
                                                    const float* __restrict__ wkv,
                                                    const float* __restrict__ wr,
                                                    const float* __restrict__ wo,
                                                    bf16* __restrict__ out) {
    int off = (blockIdx.x * 256 + threadIdx.x) * 8;
    const float* src;
    if (off < 1048576)       src = wq + off;
    else if (off < 3145728)  src = wkv + (off - 1048576);
    else if (off < 4194304)  src = wr + (off - 3145728);
    else                     src = wo + (off - 4194304);
    float4 f0 = *(const float4*)src;
    float4 f1 = *(const float4*)(src + 4);
    s16x8 v;
    v[0] = (short)bbu(f0.x); v[1] = (short)bbu(f0.y);
    v[2] = (short)bbu(f0.z); v[3] = (short)bbu(f0.w);
    v[4] = (short)bbu(f1.x); v[5] = (short)bbu(f1.y);
    v[6] = (short)bbu(f1.z); v[7] = (short)bbu(f1.w);
    *(s16x8*)((short*)out + off) = v;
}

// ---------------------------------------------------------------------------
// LayerNorm of content+mems into cat[KLEN*BSZ, DMODEL] (bf16).
// ---------------------------------------------------------------------------
__global__ __launch_bounds__(256) void ln_kernel(const float* __restrict__ content,
                                                 const float* __restrict__ mems,
                                                 const float* __restrict__ g,
                                                 const float* __restrict__ bet,
                                                 bf16* __restrict__ cat) {
    int row = blockIdx.x;
    int tid = threadIdx.x;
    const float* src = (row < MLENC * BSZ)
        ? mems + (size_t)row * DMODEL
        : content + (size_t)(row - MLENC * BSZ) * DMODEL;

    float x[4];
    float s = 0.f, ss = 0.f;
#pragma unroll
    for (int l = 0; l < 4; ++l) {
        int d = l * 256 + tid;
        x[l] = src[d];
        s += x[l];
        ss += x[l] * x[l];
    }
#pragma unroll
    for (int off = 32; off > 0; off >>= 1) {
        s  += __shfl_xor(s, off);
        ss += __shfl_xor(ss, off);
    }
    __shared__ float red[8];
    int wid = tid >> 6;
    if ((tid & 63) == 0) { red[wid * 2] = s; red[wid * 2 + 1] = ss; }
    __syncthreads();
    s  = red[0] + red[2] + red[4] + red[6];
    ss = red[1] + red[3] + red[5] + red[7];
    float mu  = s * (1.f / DMODEL);
    float var = ss * (1.f / DMODEL) - mu * mu;
    float rs  = rsqrtf(var + 1e-5f);
    bf16* dst = cat + (size_t)row * DMODEL;
#pragma unroll
    for (int l = 0; l < 4; ++l) {
        int d = l * 256 + tid;
        dst[d] = f2b((x[l] - mu) * rs * g[d] + bet[d]);
    }
}

// ---------------------------------------------------------------------------
// MFMA GEMM 128x128 tile, BK=32 (for the big kv GEMM).
// ---------------------------------------------------------------------------
template <int MODE, bool AF32, bool BF32>
__global__ __launch_bounds__(256) void gemm_mfma(const void* __restrict__ Av,
                                                 const void* __restrict__ Bv,
                                                 const float* __restrict__ bias,
                                                 const bf16* __restrict__ resid,
                                                 bf16* __restrict__ Cb,
                                                 float* __restrict__ Cf,
                                                 int Mr, int N) {
    __shared__ short As[128 * 32];
    __shared__ short Bs[128 * 32];

    int m0 = blockIdx.y * 128, n0 = blockIdx.x * 128;
    int tid = threadIdx.x;
    int w = tid >> 6, lane = tid & 63, l15 = lane & 15, quad = lane >> 4;
    int wm = w & 1, wn = w >> 1;

    const short* Ab = (const short*)Av;
    const float* Af = (const float*)Av;
    const short* Bb = (const short*)Bv;
    const float* Bf = (const float*)Bv;

    f32x4 acc[4][4];
#pragma unroll
    for (int i = 0; i < 4; ++i)
#pragma unroll
        for (int j = 0; j < 4; ++j) acc[i][j] = (f32x4){0.f, 0.f, 0.f, 0.f};

    for (int kt = 0; kt < 1024; kt += 32) {
        __syncthreads();
        if (!AF32) {
#pragma unroll
            for (int li = 0; li < 2; ++li) {
                int id = (li * 4 + w) * 64 + lane;
                int row = id >> 2, kc = (id & 3) * 8;
                gl_lds16(Ab + ((size_t)(m0 + row) * 1024 + kt + kc),
                         &As[(li * 4 + w) * 512]);
            }
        } else {
            int m = tid >> 1, kc = (tid & 1) * 16;
            const float* src = Af + (size_t)(m0 + m) * 1024 + kt + kc;
            u32* dst = (u32*)&As[m * 32 + kc];
#pragma unroll
            for (int q2 = 0; q2 < 4; ++q2) {
                float4 f = *(const float4*)(src + q2 * 4);
                dst[q2 * 2]     = ((u32)bbu(f.y) << 16) | bbu(f.x);
                dst[q2 * 2 + 1] = ((u32)bbu(f.w) << 16) | bbu(f.z);
            }
        }
        if (!BF32) {
#pragma unroll
            for (int li = 0; li < 2; ++li) {
                int id = (li * 4 + w) * 64 + lane;
                int row = id >> 2, kc = (id & 3) * 8;
                gl_lds16(Bb + ((size_t)(n0 + row) * 1024 + kt + kc),
                         &Bs[(li * 4 + w) * 512]);
            }
        } else {
            int nn = tid >> 1, kc = (tid & 1) * 16;
            const float* src = Bf + (size_t)(n0 + nn) * 1024 + kt + kc;
            u32* dst = (u32*)&Bs[nn * 32 + kc];
#pragma unroll
            for (int q2 = 0; q2 < 4; ++q2) {
                float4 f = *(const float4*)(src + q2 * 4);
                dst[q2 * 2]     = ((u32)bbu(f.y) << 16) | bbu(f.x);
                dst[q2 * 2 + 1] = ((u32)bbu(f.w) << 16) | bbu(f.z);
            }
        }
        __syncthreads();

        s16x8 af[4], bfr[4];
#pragma unroll
        for (int mb = 0; mb < 4; ++mb)
            af[mb] = *(const s16x8*)&As[(wm * 64 + mb * 16 + l15) * 32 + quad * 8];
#pragma unroll
        for (int nb = 0; nb < 4; ++nb)
            bfr[nb] = *(const s16x8*)&Bs[(wn * 64 + nb * 16 + l15) * 32 + quad * 8];
#pragma unroll
        for (int mb = 0; mb < 4; ++mb)
#pragma unroll
            for (int nb = 0; nb < 4; ++nb)
                acc[mb][nb] = MFMA16(af[mb], bfr[nb], acc[mb][nb]);
    }

#pragma unroll
    for (int mb = 0; mb < 4; ++mb) {
#pragma unroll
        for (int nb = 0; nb < 4; ++nb) {
#pragma unroll
            for (int r = 0; r < 4; ++r) {
                int m = m0 + wm * 64 + mb * 16 + quad * 4 + r;
                int col = n0 + wn * 64 + nb * 16 + l15;
                float v = acc[mb][nb][r];
                if (MODE >= 1) v += bias[col];
                if (MODE == 2) {
                    float rv = b2f(resid[(size_t)m * N + col]);
                    Cf[(size_t)m * N + col] = rv + fmaxf(v, 0.f);
                } else {
                    Cb[(size_t)m * N + col] = f2b(v);
                }
            }
        }
    }
}

// ---------------------------------------------------------------------------
// MFMA GEMM 64x128 tile (doubles grid for the small M GEMMs q/r/o).
// ---------------------------------------------------------------------------
template <int MODE, bool AF32, bool BF32>
__global__ __launch_bounds__(256) void gemm64(const void* __restrict__ Av,
                                              const void* __restrict__ Bv,
                                              const float* __restrict__ bias,
                                              const bf16* __restrict__ resid,
                                              bf16* __restrict__ Cb,
                                              float* __restrict__ Cf,
                                              int Mr, int N) {
    __shared__ short As[64 * 32];
    __shared__ short Bs[128 * 32];

    int m0 = blockIdx.y * 64, n0 = blockIdx.x * 128;
    int tid = threadIdx.x;
    int w = tid >> 6, lane = tid & 63, l15 = lane & 15, quad = lane >> 4;

    const short* Ab = (const short*)Av;
    const float* Af = (const float*)Av;
    const short* Bb = (const short*)Bv;
    const float* Bf = (const float*)Bv;

    f32x4 acc[4][2];
#pragma unroll
    for (int i = 0; i < 4; ++i)
#pragma unroll
        for (int j = 0; j < 2; ++j) acc[i][j] = (f32x4){0.f, 0.f, 0.f, 0.f};

    for (int kt = 0; kt < 1024; kt += 32) {
        __syncthreads();
        if (!AF32) {
            int id = w * 64 + lane;
            int row = id >> 2, kc = (id & 3) * 8;
            gl_lds16(Ab + ((size_t)(m0 + row) * 1024 + kt + kc), &As[w * 512]);
        } else {
            int m = tid >> 2, kc = (tid & 3) * 8;
            const float* src = Af + (size_t)(m0 + m) * 1024 + kt + kc;
            u32* dst = (u32*)&As[m * 32 + kc];
#pragma unroll
            for (int q2 = 0; q2 < 2; ++q2) {
                float4 f = *(const float4*)(src + q2 * 4);
                dst[q2 * 2]     = ((u32)bbu(f.y) << 16) | bbu(f.x);
                dst[q2 * 2 + 1] = ((u32)bbu(f.w) << 16) | bbu(f.z);
            }
        }
        if (!BF32) {
#pragma unroll
            for (int li = 0; li < 2; ++li) {
                int id = (li * 4 + w) * 64 + lane;
                int row = id >> 2, kc = (id & 3) * 8;
                gl_lds16(Bb + ((size_t)(n0 + row) * 1024 + kt + kc),
                         &Bs[(li * 4 + w) * 512]);
            }
        } else {
            int nn = tid >> 1, kc = (tid & 1) * 16;
            const float* src = Bf + (size_t)(n0 + nn) * 1024 + kt + kc;
            u32* dst = (u32*)&Bs[nn * 32 + kc];
#pragma unroll
            for (int q2 = 0; q2 < 4; ++q2) {
                float4 f = *(const float4*)(src + q2 * 4);
                dst[q2 * 2]     = ((u32)bbu(f.y) << 16) | bbu(f.x);
                dst[q2 * 2 + 1] = ((u32)bbu(f.w) << 16) | bbu(f.z);
            }
        }
        __syncthreads();

        s16x8 af[4], bfr[2];
#pragma unroll
        for (int mb = 0; mb < 4; ++mb)
            af[mb] = *(const s16x8*)&As[(mb * 16 + l15) * 32 + quad * 8];
#pragma unroll
        for (int nb = 0; nb < 2; ++nb)
            bfr[nb] = *(const s16x8*)&Bs[(w * 32 + nb * 16 + l15) * 32 + quad * 8];
#pragma unroll
        for (int mb = 0; mb < 4; ++mb)
#pragma unroll
            for (int nb = 0; nb < 2; ++nb)
                acc[mb][nb] = MFMA16(af[mb], bfr[nb], acc[mb][nb]);
    }

#pragma unroll
    for (int mb = 0; mb < 4; ++mb) {
#pragma unroll
        for (int nb = 0; nb < 2; ++nb) {
#pragma unroll
            for (int r = 0; r < 4; ++r) {
                int m = m0 + mb * 16 + quad * 4 + r;
                int col = n0 + w * 32 + nb * 16 + l15;
                float v = acc[mb][nb][r];
                if (MODE >= 1) v += bias[col];
                if (MODE == 2) {
                    float rv = b2f(resid[(size_t)m * N + col]);
                    Cf[(size_t)m * N + col] = rv + fmaxf(v, 0.f);
                } else {
                    Cb[(size_t)m * N + col] = f2b(v);
                }
            }
        }
    }
}

// ---------------------------------------------------------------------------
// Fused MFMA flash attention, KVBLK=64 (halves per-step fixed costs vs 32:
// barriers, softmax shuffle chains, bandM lgkm round-trips, loop overhead).
// Rel-shift on the fly: with d0 = j0 - i0 (multiple of 64),
//   band1 (u = 511 + (j-i), q-row i)   needed iff d0 <= 512
//   band2 (u = (j-i) - 514, q-row i+1) needed iff d0 >= 512
// exactly one mixed step per block (d0 == 512). W fragments (10/band) are
// JIT-loaded from L2-resident rp, issued before AC so QK^T covers latency.
// ---------------------------------------------------------------------------
__global__ __launch_bounds__(256, 2) void attn_mfma(const bf16* __restrict__ qb,
                                                    const bf16* __restrict__ kv,
                                                    const bf16* __restrict__ rp,
                                                    bf16* __restrict__ vec) {
    __shared__ u16 Ks[64][72];     // K tile [j][d]            18,432 B
    __shared__ u16 Vr[2][4096];    // V tile raw ping-pong     16,384 B
    __shared__ u16 Vt[64][72];     // V transposed [d][j]      18,432 B
    __shared__ u16 Ps[4][16][76];  // per-wave P [row][col]     9,728 B
    __shared__ u16 Ms[4][16][92];  // per-wave band strip      11,776 B

    int bid = blockIdx.x;
    int it = bid & 7, n = (bid >> 3) & 15, b = bid >> 7;
    int i0 = it * 64;
    int tid = threadIdx.x;
    int w = tid >> 6, lane = tid & 63, l15 = lane & 15, quad = lane >> 4;

    const short* qs = (const short*)qb;
    const short* kvs = (const short*)kv;
    const short* rs = (const short*)rp;

    // Q fragments: rows +0 (aq) and +1 (as, for wrap branch)
    size_t qoff = (((size_t)(i0 + w * 16 + l15) * 8) + b) * 1024 + n * 64 + quad * 8;
    s16x8 aq0 = *(const s16x8*)(qs + qoff);
    s16x8 aq1 = *(const s16x8*)(qs + qoff + 32);
    int qrow1 = i0 + w * 16 + l15 + 1; if (qrow1 > 511) qrow1 = 511;  // unused when clamped
    size_t qoffs = (((size_t)qrow1 * 8) + b) * 1024 + n * 64 + quad * 8;
    s16x8 as0 = *(const s16x8*)(qs + qoffs);
    s16x8 as1 = *(const s16x8*)(qs + qoffs + 32);

    f32x4 O0 = {0.f,0.f,0.f,0.f}, O1 = O0, O2 = O0, O3 = O0;
    float mrun[4], lrun[4];
#pragma unroll
    for (int r = 0; r < 4; ++r) { mrun[r] = -INFINITY; lrun[r] = 0.f; }

    f32x4 z = (f32x4){0.f, 0.f, 0.f, 0.f};
    int ibase = i0 + w * 16 + quad * 4;

    int r0K = tid >> 3, c0K = (tid & 7) * 8;   // K/V stage mapping (rows 0..31; +32 for e=1)
    int dV = lane, jV = w * 16;                // V transpose mapping
    int wrow = (3 - w) * 16 + l15;             // W-window row offset for this wave

    // load 10 W-fragments (5 tiles x 2 k-halves) for window base `ubase`
    auto loadW = [&](int ubase, s16x8* dst) {
#pragma unroll
        for (int ntl = 0; ntl < 5; ++ntl) {
            int u = ubase + wrow + ntl * 16;
            u = u < 0 ? 0 : (u > 1023 ? 1023 : u);
            const short* p = rs + (size_t)u * 1024 + n * 64 + quad * 8;
            dst[ntl * 2]     = *(const s16x8*)p;
            dst[ntl * 2 + 1] = *(const s16x8*)(p + 32);
        }
    };
    // banded matmul + anti-diagonal gather (per-wave, same-wave DS ordering)
    // th[h][r] = BD for score col group h, acc row r
    auto bandM = [&](const s16x8* wf, s16x8 a0, s16x8 a1, f32x4* th) {
        f32x4 m[5];
#pragma unroll
        for (int ntl = 0; ntl < 5; ++ntl) {
            m[ntl] = MFMA16(a0, wf[ntl * 2], z);
            m[ntl] = MFMA16(a1, wf[ntl * 2 + 1], m[ntl]);
        }
#pragma unroll
        for (int ntl = 0; ntl < 5; ++ntl)
#pragma unroll
            for (int r = 0; r < 4; ++r)
                Ms[w][quad * 4 + r][ntl * 16 + l15] = bbu(m[ntl][r]);
        __asm__ __volatile__("s_waitcnt lgkmcnt(0)" ::: "memory");
#pragma unroll
        for (int r = 0; r < 4; ++r) {
            int lr = quad * 4 + r;
            int cb = l15 - lr + 15;
#pragma unroll
            for (int h = 0; h < 4; ++h)
                th[h][r] = sh2f(Ms[w][lr][cb + 16 * h]);
        }
        __asm__ __volatile__("s_waitcnt lgkmcnt(0)" ::: "memory");
    };

    // prologue: stage K tile 0 (regs->LDS), glds V tile 0 into Vr[0]
    {
        size_t base0 = ((size_t)(r0K * 8 + b)) * 2048 + n * 64 + c0K;
        size_t base1 = ((size_t)((32 + r0K) * 8 + b)) * 2048 + n * 64 + c0K;
        s16x8 k0 = *(const s16x8*)(kvs + base0);
        s16x8 k1 = *(const s16x8*)(kvs + base1);
        gl_lds16(kvs + base0 + 1024, &Vr[0][w * 512]);
        gl_lds16(kvs + base1 + 1024, &Vr[0][2048 + w * 512]);
        *(s16x8*)&Ks[r0K][c0K] = k0;
        *(s16x8*)&Ks[32 + r0K][c0K] = k1;
    }

    for (int st = 0; st < 16; ++st) {
        int p = st & 1;
        int j0 = st * 64;
        int d0 = j0 - i0;
        int j0n = (j0 + 64) & 1023;        // wrapped for addressing safety on last iter

        __syncthreads();   // barrier A: prev PV done; Ks/Vr[p] visible

        // ---- JIT W loads (L2-resident rp); issued early so AC covers latency
        bool need1 = (d0 <= 512);
        bool need2 = (d0 >= 512);
        s16x8 wf1[10];
        if (need1) loadW(448 + d0, wf1);

        // ---- prefetch next K/V tile ----
        size_t base0 = ((size_t)((j0n + r0K) * 8 + b)) * 2048 + n * 64 + c0K;
        size_t base1 = ((size_t)((j0n + 32 + r0K) * 8 + b)) * 2048 + n * 64 + c0K;
        s16x8 kr0 = *(const s16x8*)(kvs + base0);
        s16x8 kr1 = *(const s16x8*)(kvs + base1);
        gl_lds16(kvs + base0 + 1024, &Vr[1 - p][w * 512]);
        gl_lds16(kvs + base1 + 1024, &Vr[1 - p][2048 + w * 512]);

        // ---- transpose Vr[p] -> Vt (this wave's 16 j-rows) ----
        {
            s16x8 vv0, vv1;
#pragma unroll
            for (int q2 = 0; q2 < 8; ++q2) vv0[q2] = (short)Vr[p][(jV + q2) * 64 + dV];
#pragma unroll
            for (int q2 = 0; q2 < 8; ++q2) vv1[q2] = (short)Vr[p][(jV + 8 + q2) * 64 + dV];
            *(s16x8*)&Vt[dV][jV] = vv0;
            *(s16x8*)&Vt[dV][jV + 8] = vv1;
        }

        // ---- AC = Q K^T (4 col-groups x 2 k-halves) ----
        f32x4 sc[4];
#pragma unroll
        for (int h = 0; h < 4; ++h) {
            s16x8 bk0 = *(const s16x8*)&Ks[h * 16 + l15][quad * 8];
            s16x8 bk1 = *(const s16x8*)&Ks[h * 16 + l15][32 + quad * 8];
            sc[h] = MFMA16(aq0, bk0, z);
            sc[h] = MFMA16(aq1, bk1, sc[h]);
        }

        // ---- BD bands ----
        f32x4 th1[4], th2[4];
#pragma unroll
        for (int h = 0; h < 4; ++h) { th1[h] = z; th2[h] = z; }
        if (need1) bandM(wf1, aq0, aq1, th1);
        if (need2) {
            s16x8 wf2[10];
            loadW(d0 - 577, wf2);
            bandM(wf2, as0, as1, th2);
        }

        // ---- select + scale ----
#pragma unroll
        for (int r = 0; r < 4; ++r) {
            int rr = w * 16 + quad * 4 + r;
            int djb = j0 + l15 - i0 - rr;
#pragma unroll
            for (int h = 0; h < 4; ++h) {
                int dj = djb + 16 * h;
                float bd = (dj <= 512) ? th1[h][r] : ((dj == 513) ? 0.f : th2[h][r]);
                sc[h][r] = (sc[h][r] + bd) * 0.125f;
            }
        }

        // ---- online softmax + P to LDS ----
#pragma unroll
        for (int r = 0; r < 4; ++r) {
            float ml = fmaxf(fmaxf(sc[0][r], sc[1][r]), fmaxf(sc[2][r], sc[3][r]));
            ml = fmaxf(ml, __shfl_xor(ml, 1));
            ml = fmaxf(ml, __shfl_xor(ml, 2));
            ml = fmaxf(ml, __shfl_xor(ml, 4));
            ml = fmaxf(ml, __shfl_xor(ml, 8));
            float mn = fmaxf(mrun[r], ml);
            float p0 = __expf(sc[0][r] - mn);
            float p1 = __expf(sc[1][r] - mn);
            float p2 = __expf(sc[2][r] - mn);
            float p3 = __expf(sc[3][r] - mn);
            float ps = (p0 + p1) + (p2 + p3);
            ps += __shfl_xor(ps, 1);
            ps += __shfl_xor(ps, 2);
            ps += __shfl_xor(ps, 4);
            ps += __shfl_xor(ps, 8);
            float al = __expf(mrun[r] - mn);
            lrun[r] = lrun[r] * al + ps;
            mrun[r] = mn;
            O0[r] *= al; O1[r] *= al; O2[r] *= al; O3[r] *= al;
            int lr = quad * 4 + r;
            Ps[w][lr][l15]      = bbu(p0);
            Ps[w][lr][16 + l15] = bbu(p1);
            Ps[w][lr][32 + l15] = bbu(p2);
            Ps[w][lr][48 + l15] = bbu(p3);
        }

        __syncthreads();   // barrier B: Vt+Ps visible; drains V glds

        // ---- PV (2 k-halves x 4 d-blocks) ----
        s16x8 ap0 = *(const s16x8*)&Ps[w][l15][quad * 8];
        s16x8 ap1 = *(const s16x8*)&Ps[w][l15][32 + quad * 8];
        {
            s16x8 bv0 = *(const s16x8*)&Vt[l15][quad * 8];
            s16x8 bv1 = *(const s16x8*)&Vt[l15][32 + quad * 8];
            O0 = MFMA16(ap0, bv0, O0);
            O0 = MFMA16(ap1, bv1, O0);
        }
        {
            s16x8 bv0 = *(const s16x8*)&Vt[16 + l15][quad * 8];
            s16x8 bv1 = *(const s16x8*)&Vt[16 + l15][32 + quad * 8];
            O1 = MFMA16(ap0, bv0, O1);
            O1 = MFMA16(ap1, bv1, O1);
        }
        {
            s16x8 bv0 = *(const s16x8*)&Vt[32 + l15][quad * 8];
            s16x8 bv1 = *(const s16x8*)&Vt[32 + l15][32 + quad * 8];
            O2 = MFMA16(ap0, bv0, O2);
            O2 = MFMA16(ap1, bv1, O2);
        }
        {
            s16x8 bv0 = *(const s16x8*)&Vt[48 + l15][quad * 8];
            s16x8 bv1 = *(const s16x8*)&Vt[48 + l15][32 + quad * 8];
            O3 = MFMA16(ap0, bv0, O3);
            O3 = MFMA16(ap1, bv1, O3);
        }

        // ---- stage next K tile ----
        *(s16x8*)&Ks[r0K][c0K] = kr0;
        *(s16x8*)&Ks[32 + r0K][c0K] = kr1;
    }

#pragma unroll
    for (int r = 0; r < 4; ++r) {
        float inv = 1.f / lrun[r];
        int ig = ibase + r;
        size_t o = ((size_t)ig * 8 + b) * 1024 + n * 64;
        vec[o + l15]      = f2b(O0[r] * inv);
        vec[o + 16 + l15] = f2b(O1[r] * inv);
        vec[o + 32 + l15] = f2b(O2[r] * inv);
        vec[o + 48 + l15] = f2b(O3[r] * inv);
    }
}

// ---------------------------------------------------------------------------
extern "C" void kernel_launch(void* const* d_in, const int* in_sizes, int n_in,
                              void* d_out, int out_size, void* d_ws, size_t ws_size,
                              hipStream_t stream) {
    const float* content = (const float*)d_in[0];
    const float* mems    = (const float*)d_in[1];
    const float* r       = (const float*)d_in[2];
    const float* q_bias  = (const float*)d_in[3];
    // d_in[4] = mask (all false) -> ignored
    const float* W_q     = (const float*)d_in[5];
    const float* W_kv    = (const float*)d_in[6];
    const float* W_r     = (const float*)d_in[7];
    const float* b_r     = (const float*)d_in[8];
    const float* W_o     = (const float*)d_in[9];
    const float* b_o     = (const float*)d_in[10];
    const float* ln_g    = (const float*)d_in[11];
    const float* ln_b    = (const float*)d_in[12];

    bf16* ws   = (bf16*)d_ws;
    bf16* cat  = ws;                       // [8192,1024]
    bf16* kv   = cat + 8388608;            // [8192,2048]
    bf16* qb   = kv + 16777216;            // [4096,1024]
    bf16* rp   = qb + 4194304;             // [1024,1024]
    bf16* vecb = rp + 1048576;             // [4096,1024]
    bf16* Wb   = vecb + 4194304;           // 5,242,880 bf16 weights
    bf16* catc = cat + (size_t)MLENC * BSZ * DMODEL;

    bf16* Wqb  = Wb;
    bf16* Wkvb = Wb + 1048576;
    bf16* Wrb  = Wb + 3145728;
    bf16* Wob  = Wb + 4194304;

    const size_t FULLW_BYTES = (size_t)(34603008 + 5242880) * 2;  // 79,691,776
    bool fullw = ws_size >= FULLW_BYTES;

    ln_kernel<<<KLEN * BSZ, 256, 0, stream>>>(content, mems, ln_g, ln_b, cat);

    if (fullw) {
        wconv_kernel<<<2560, 256, 0, stream>>>(W_q, W_kv, W_r, W_o, Wb);

        gemm_mfma<0, false, false><<<dim3(16, 64), 256, 0, stream>>>(
            cat, Wkvb, nullptr, nullptr, kv, nullptr, 8192, 2048);
        gemm64<1, false, false><<<dim3(8, 64), 256, 0, stream>>>(
            catc, Wqb, q_bias, nullptr, qb, nullptr, 4096, 1024);
        gemm64<1, true, false><<<dim3(8, 16), 256, 0, stream>>>(
            r, Wrb, b_r, nullptr, rp, nullptr, 1024, 1024);
    } else {
        gemm_mfma<0, false, true><<<dim3(16, 64), 256, 0, stream>>>(
            cat, W_kv, nullptr, nullptr, kv, nullptr, 8192, 2048);
        gemm64<1, false, true><<<dim3(8, 64), 256, 0, stream>>>(
            catc, W_q, q_bias, nullptr, qb, nullptr, 4096, 1024);
        gemm64<1, true, true><<<dim3(8, 16), 256, 0, stream>>>(
            r, W_r, b_r, nullptr, rp, nullptr, 1024, 1024);
    }

    attn_mfma<<<BSZ * NHEAD * 8, 256, 0, stream>>>(qb, kv, rp, vecb);

    if (fullw) {
        gemm64<2, false, false><<<dim3(8, 64), 256, 0, stream>>>(
            vecb, Wob, b_o, catc, nullptr, (float*)d_out, 4096, 1024);
    } else {
        gemm64<2, false, true><<<dim3(8, 64), 256, 0, stream>>>(
            vecb, W_o, b_o, catc, nullptr, (float*)d_out, 4096, 1024);
    }
}